// Round 5
// baseline (249.393 us; speedup 1.0000x reference)
//
#include <hip/hip_runtime.h>
#include <math.h>

// ---- problem constants (match reference) ----
#define NCOLS   407
#define RAD_OFF 87
#define ANG_OFF 151

// shiftR[r] = 0.8 + r*0.275  (r=0..15)
// shiftA[a] = 0.8 + a*0.675  (a=0..3)
// shiftZ[z] = pi/8 + z*pi/4  (z=0..3)

// ============ init: zero counts + per-atom valence table ============
__global__ __launch_bounds__(256) void init_kernel(const int* __restrict__ species,
                                                   const float4* __restrict__ valence,
                                                   float4* __restrict__ val_atom,
                                                   int* __restrict__ counts,
                                                   int n_atoms) {
    int idx = blockIdx.x * 256 + threadIdx.x;
    if (idx < 2 * n_atoms) counts[idx] = 0;
    if (idx < n_atoms) val_atom[idx] = valence[species[idx]];
}

// ============ histograms + per-angular-edge table ============
__global__ __launch_bounds__(256) void hist_edata_kernel(const int* __restrict__ esrc,
                                                         const int* __restrict__ central,
                                                         const float* __restrict__ ang_dist,
                                                         const float* __restrict__ ang_sw,
                                                         const int* __restrict__ ang_edge_dst,
                                                         const float4* __restrict__ val_atom,
                                                         int* __restrict__ rad_counts,
                                                         int* __restrict__ ang_counts,
                                                         float2* __restrict__ edata_ds,
                                                         float4* __restrict__ edata_v,
                                                         int n_edges, int n_pairs, int n_ang_edges) {
    int i = blockIdx.x * 256 + threadIdx.x;
    if (i < n_edges) {
        atomicAdd(&rad_counts[esrc[i]], 1);
    } else {
        int p = i - n_edges;
        if (p < n_pairs) atomicAdd(&ang_counts[central[p]], 1);
    }
    if (i < n_ang_edges) {
        edata_ds[i] = make_float2(ang_dist[i], ang_sw[i]);
        edata_v[i]  = val_atom[ang_edge_dst[i]];
    }
}

// ============ fused scan: block 0 = radial, block 1 = angular ============
// counts[] is overwritten in-place with the exclusive prefix (serves as cursor)
__global__ __launch_bounds__(1024) void scan_kernel(int* __restrict__ rad_counts,
                                                    int* __restrict__ ang_counts,
                                                    int* __restrict__ rad_offsets,
                                                    int* __restrict__ ang_offsets,
                                                    int n) {
    int* counts  = (blockIdx.x == 0) ? rad_counts  : ang_counts;
    int* offsets = (blockIdx.x == 0) ? rad_offsets : ang_offsets;
    __shared__ int part[1024];
    int t = threadIdx.x;
    int C = (n + 1023) >> 10;
    int lo = min(t * C, n);
    int hi = min(lo + C, n);
    int s = 0;
    for (int i = lo; i < hi; ++i) s += counts[i];
    part[t] = s;
    __syncthreads();
    for (int off = 1; off < 1024; off <<= 1) {
        int v = (t >= off) ? part[t - off] : 0;
        __syncthreads();
        part[t] += v;
        __syncthreads();
    }
    int run = part[t] - s;   // exclusive base for this thread's range
    for (int i = lo; i < hi; ++i) {
        int c = counts[i];
        offsets[i] = run;
        counts[i]  = run;    // cursor
        run += c;
    }
    if (t == 1023) offsets[n] = part[1023];
}

// ============ fused phase A ============
// radial blocks [0, nb_rad): val gather + cursor/perm scatter
// angular blocks [nb_rad, ...): compute 16 floats/pair, LDS-transpose, stream
__global__ __launch_bounds__(256) void phaseA_kernel(
    const int* __restrict__ esrc, const int* __restrict__ edst,
    const float* __restrict__ ang_angles,
    const int* __restrict__ psrc, const int* __restrict__ pdst,
    const int* __restrict__ central,
    const float4* __restrict__ val_atom,
    const float2* __restrict__ edata_ds, const float4* __restrict__ edata_v,
    int* __restrict__ rad_cursor, int* __restrict__ ang_cursor,
    float4* __restrict__ rad_pay_v, int* __restrict__ rad_perm,
    float4* __restrict__ ang_payload, int* __restrict__ ang_perm,
    int n_edges, int n_pairs, int nb_rad)
{
    __shared__ float buf[16][257];
    int bid = blockIdx.x;
    int t = threadIdx.x;

    if (bid < nb_rad) {
        int i = bid * 256 + t;
        if (i < n_edges) {
            rad_pay_v[i] = val_atom[edst[i]];
            int slot = atomicAdd(&rad_cursor[esrc[i]], 1);
            rad_perm[slot] = i;
        }
        return;
    }

    int p0 = (bid - nb_rad) * 256;
    int valid = min(256, n_pairs - p0);
    int p = p0 + t;
    if (t < valid) {
        int e1 = psrc[p];
        int e2 = pdst[p];
        float2 ds1 = edata_ds[e1];
        float2 ds2 = edata_ds[e2];
        float4 v1  = edata_v[e1];
        float4 v2  = edata_v[e2];
        float d12 = 0.5f * (ds1.x + ds2.x);
        float swp = 2.0f * ds1.y * ds2.y;

        float sa, ca;
        __sincosf(ang_angles[p], &sa, &ca);
        // cos(ang - shiftZ) = ca*cos(shiftZ) + sa*sin(shiftZ)
        const float czv[4] = { 0.92387953f,  0.38268343f, -0.38268343f, -0.92387953f };
        const float szv[4] = { 0.38268343f,  0.92387953f,  0.92387953f,  0.38268343f };
        #pragma unroll
        for (int z = 0; z < 4; ++z) {
            float y = 0.5f + 0.5f * (ca * czv[z] + sa * szv[z]);
            float y2 = y * y, y4 = y2 * y2, y8 = y4 * y4, y16 = y8 * y8;
            buf[4 + z][t] = y16 * y16;  // f1
        }
        #pragma unroll
        for (int a = 0; a < 4; ++a) {
            float x = d12 - (0.8f + 0.675f * (float)a);
            buf[a][t] = swp * __expf(-8.0f * x * x);  // f2s
        }
        buf[ 8][t] = v1.x + v2.x;  buf[ 9][t] = v1.y + v2.y;
        buf[10][t] = v1.z + v2.z;  buf[11][t] = v1.w + v2.w;
        buf[12][t] = v1.x * v2.x;  buf[13][t] = v1.y * v2.y;
        buf[14][t] = v1.z * v2.z;  buf[15][t] = v1.w * v2.w;

        int slot = atomicAdd(&ang_cursor[central[p]], 1);
        ang_perm[slot] = p;
    }
    __syncthreads();
    // stream payload: valid*16 floats, contiguous from (size_t)p0*16
    float4* dst = (float4*)ang_payload + (size_t)p0 * 4;
    int nf4 = valid * 4;
    #pragma unroll
    for (int c = 0; c < 4; ++c) {
        int F = c * 256 + t;
        if (F < nf4) {
            int pp = F >> 2, k0 = (F & 3) * 4;
            dst[F] = make_float4(buf[k0][pp], buf[k0 + 1][pp],
                                 buf[k0 + 2][pp], buf[k0 + 3][pp]);
        }
    }
}

// ============ fused phase B ============
// blocks [0, n_atoms): angular 256 cols; blocks [n_atoms, 2n): radial 64 cols + onehot
__global__ __launch_bounds__(256) void phaseB_kernel(
    const float* __restrict__ ang_payload, const int* __restrict__ ang_perm,
    const int* __restrict__ ang_offsets,
    const float* __restrict__ dist, const float* __restrict__ sw,
    const float4* __restrict__ rad_pay_v, const int* __restrict__ rad_perm,
    const int* __restrict__ rad_offsets,
    const int* __restrict__ species,
    float* __restrict__ out, int n_atoms)
{
    __shared__ float sbuf[512];
    int bid = blockIdx.x;
    int t = threadIdx.x;

    if (bid < n_atoms) {
        // ---- angular: 256 columns ----
        int atom = bid;
        int beg = ang_offsets[atom];
        int end = ang_offsets[atom + 1];
        int a = t >> 6, z = (t >> 4) & 3, i = (t >> 2) & 3, j = t & 3;
        int g = t >> 4, jj = t & 15;   // 16 pairs/chunk, 16 lanes/pair
        float acc = 0.0f;
        for (int base = beg; base < end; base += 16) {
            int rem = end - base;
            if (g < rem) {
                int pp = ang_perm[base + g];
                sbuf[t] = ang_payload[(size_t)pp * 16 + jj];
            }
            __syncthreads();
            int cnt = min(16, rem);
            if (cnt == 16) {
                #pragma unroll
                for (int e = 0; e < 16; ++e) {
                    float f2s = sbuf[e * 16 + a];
                    float f1  = sbuf[e * 16 + 4 + z];
                    float vp  = sbuf[e * 16 + 8 + i];
                    float vm  = sbuf[e * 16 + 12 + j];
                    acc += (f2s * f1) * (vp * vm);
                }
            } else {
                for (int e = 0; e < cnt; ++e) {
                    float f2s = sbuf[e * 16 + a];
                    float f1  = sbuf[e * 16 + 4 + z];
                    float vp  = sbuf[e * 16 + 8 + i];
                    float vm  = sbuf[e * 16 + 12 + j];
                    acc += (f2s * f1) * (vp * vm);
                }
            }
            __syncthreads();
        }
        out[(size_t)atom * NCOLS + ANG_OFF + t] = acc;
        return;
    }

    // ---- radial: 64 columns, 4-way split over edges + reduce; plus onehot ----
    int atom = bid - n_atoms;
    int beg = rad_offsets[atom];
    int end = rad_offsets[atom + 1];
    float* buf  = sbuf;        // [256] : 32 edges x 8 floats
    float* part = sbuf + 256;  // [256]
    int g = t >> 3, j = t & 7;         // staging: 32 edges, 8 lanes/edge
    int col = t & 63, s = t >> 6;      // compute: col 0..63, subset 0..3
    int r = col >> 2, k = col & 3;
    float shift = 0.8f + 0.275f * (float)r;
    float acc = 0.0f;
    for (int base = beg; base < end; base += 32) {
        int rem = end - base;
        int cnt = min(32, rem);
        if (g < cnt) {
            int pp = rad_perm[base + g];
            float x = 0.0f;
            if (j == 0)      x = dist[pp];
            else if (j == 1) x = 0.25f * sw[pp];
            else if (j < 6)  x = ((const float*)rad_pay_v)[(size_t)pp * 4 + (j - 2)];
            buf[g * 8 + j] = x;
        }
        __syncthreads();
        int elo = s * 8, ehi = min(elo + 8, cnt);
        for (int e = elo; e < ehi; ++e) {
            float d  = buf[e * 8 + 0];
            float ps = buf[e * 8 + 1];
            float v  = buf[e * 8 + 2 + k];
            float x = d - shift;
            acc += ps * __expf(-16.0f * x * x) * v;
        }
        __syncthreads();
    }
    part[t] = acc;
    __syncthreads();
    if (t < 64) {
        float sum = part[t] + part[t + 64] + part[t + 128] + part[t + 192];
        out[(size_t)atom * NCOLS + RAD_OFF + t] = sum;
    }
    int sp = species[atom];
    if (t < 87) out[(size_t)atom * NCOLS + t] = (t == sp) ? 1.0f : 0.0f;
}

extern "C" void kernel_launch(void* const* d_in, const int* in_sizes, int n_in,
                              void* d_out, int out_size, void* d_ws, size_t ws_size,
                              hipStream_t stream) {
    const int*   species      = (const int*)  d_in[0];
    const float* distances    = (const float*)d_in[1];
    const float* switch_      = (const float*)d_in[2];
    const int*   edge_src     = (const int*)  d_in[3];
    const int*   edge_dst     = (const int*)  d_in[4];
    const float* ang_angles   = (const float*)d_in[5];
    const float* ang_dist     = (const float*)d_in[6];
    const float* ang_switch   = (const float*)d_in[7];
    const int*   ang_edge_dst = (const int*)  d_in[8];
    const int*   angle_src    = (const int*)  d_in[9];
    const int*   angle_dst    = (const int*)  d_in[10];
    const int*   central_atom = (const int*)  d_in[11];
    const float4* valence     = (const float4*)d_in[12];

    float* out = (float*)d_out;

    const int n_atoms     = in_sizes[0];
    const int n_edges     = in_sizes[1];
    const int n_ang_edges = in_sizes[6];
    const int n_pairs     = in_sizes[5];

    // ---- workspace layout (16B-aligned), total ~= 55.4 MB ----
    char* ws = (char*)d_ws;
    size_t off = 0;
    auto alloc = [&](size_t bytes) -> void* {
        void* p = ws + off;
        off = (off + bytes + 15) & ~(size_t)15;
        return p;
    };
    float4* ang_payload = (float4*)alloc((size_t)n_pairs * 16 * sizeof(float));   // 35.84 MB
    float4* rad_pay_v   = (float4*)alloc((size_t)n_edges * sizeof(float4));       // 10.24 MB
    float4* edata_v     = (float4*)alloc((size_t)n_ang_edges * sizeof(float4));   //  2.56 MB
    float2* edata_ds    = (float2*)alloc((size_t)n_ang_edges * sizeof(float2));   //  1.28 MB
    int*    ang_perm    = (int*)  alloc((size_t)n_pairs * sizeof(int));           //  2.24 MB
    int*    rad_perm    = (int*)  alloc((size_t)n_edges * sizeof(int));           //  2.56 MB
    float4* val_atom    = (float4*)alloc((size_t)n_atoms * sizeof(float4));       //  0.32 MB
    int*    counts      = (int*)  alloc((size_t)2 * n_atoms * sizeof(int));       //  0.16 MB
    int*    rad_offsets = (int*)  alloc((size_t)(n_atoms + 1) * sizeof(int));
    int*    ang_offsets = (int*)  alloc((size_t)(n_atoms + 1) * sizeof(int));
    int* rad_counts = counts;            // doubles as cursor after scan
    int* ang_counts = counts + n_atoms;  // doubles as cursor after scan

    init_kernel<<<(2 * n_atoms + 255) / 256, 256, 0, stream>>>(
        species, valence, val_atom, counts, n_atoms);

    int n_work = n_edges + n_pairs;
    hist_edata_kernel<<<(n_work + 255) / 256, 256, 0, stream>>>(
        edge_src, central_atom, ang_dist, ang_switch, ang_edge_dst, val_atom,
        rad_counts, ang_counts, edata_ds, edata_v, n_edges, n_pairs, n_ang_edges);

    scan_kernel<<<2, 1024, 0, stream>>>(rad_counts, ang_counts, rad_offsets, ang_offsets, n_atoms);

    int nb_rad = (n_edges + 255) / 256;
    int nb_ang = (n_pairs + 255) / 256;
    phaseA_kernel<<<nb_rad + nb_ang, 256, 0, stream>>>(
        edge_src, edge_dst, ang_angles, angle_src, angle_dst, central_atom,
        val_atom, edata_ds, edata_v,
        rad_counts, ang_counts,
        rad_pay_v, rad_perm, ang_payload, ang_perm,
        n_edges, n_pairs, nb_rad);

    phaseB_kernel<<<2 * n_atoms, 256, 0, stream>>>(
        (const float*)ang_payload, ang_perm, ang_offsets,
        distances, switch_, rad_pay_v, rad_perm, rad_offsets,
        species, out, n_atoms);
}

// Round 6
// 212.436 us; speedup vs baseline: 1.1740x; 1.1740x over previous
//
#include <hip/hip_runtime.h>
#include <hip/hip_fp16.h>
#include <math.h>

// ---- problem constants (match reference) ----
#define NCOLS   407
#define RAD_OFF 87
#define ANG_OFF 151

// shiftR[r] = 0.8 + r*0.275  (r=0..15)
// shiftA[a] = 0.8 + a*0.675  (a=0..3)
// shiftZ[z] = pi/8 + z*pi/4  (z=0..3)

static __device__ inline unsigned pack2(float a, float b) {
    __half2 h = __floats2half2_rn(a, b);
    return *reinterpret_cast<unsigned*>(&h);
}
static __device__ inline float2 unpack2(unsigned u) {
    __half2 h = *reinterpret_cast<__half2*>(&u);
    return __half22float2(h);
}

// ============ init: zero counts + per-atom valence table ============
__global__ __launch_bounds__(256) void init_kernel(const int* __restrict__ species,
                                                   const float4* __restrict__ valence,
                                                   float4* __restrict__ val_atom,
                                                   int* __restrict__ counts,
                                                   int n_atoms) {
    int idx = blockIdx.x * 256 + threadIdx.x;
    if (idx < 2 * n_atoms) counts[idx] = 0;
    if (idx < n_atoms) val_atom[idx] = valence[species[idx]];
}

// ============ fused histogram ============
__global__ __launch_bounds__(256) void hist_kernel(const int* __restrict__ esrc,
                                                   const int* __restrict__ central,
                                                   int* __restrict__ rad_counts,
                                                   int* __restrict__ ang_counts,
                                                   int n_edges, int n_pairs) {
    int i = blockIdx.x * 256 + threadIdx.x;
    if (i < n_edges) {
        atomicAdd(&rad_counts[esrc[i]], 1);
    } else {
        int p = i - n_edges;
        if (p < n_pairs) atomicAdd(&ang_counts[central[p]], 1);
    }
}

// ============ fused scan: block 0 = radial, block 1 = angular ============
// counts[] is overwritten in-place with the exclusive prefix (serves as cursor)
__global__ __launch_bounds__(1024) void scan_kernel(int* __restrict__ rad_counts,
                                                    int* __restrict__ ang_counts,
                                                    int* __restrict__ rad_offsets,
                                                    int* __restrict__ ang_offsets,
                                                    int n) {
    int* counts  = (blockIdx.x == 0) ? rad_counts  : ang_counts;
    int* offsets = (blockIdx.x == 0) ? rad_offsets : ang_offsets;
    __shared__ int part[1024];
    int t = threadIdx.x;
    int C = (n + 1023) >> 10;
    int lo = min(t * C, n);
    int hi = min(lo + C, n);
    int s = 0;
    for (int i = lo; i < hi; ++i) s += counts[i];
    part[t] = s;
    __syncthreads();
    for (int off = 1; off < 1024; off <<= 1) {
        int v = (t >= off) ? part[t - off] : 0;
        __syncthreads();
        part[t] += v;
        __syncthreads();
    }
    int run = part[t] - s;   // exclusive base for this thread's range
    for (int i = lo; i < hi; ++i) {
        int c = counts[i];
        offsets[i] = run;
        counts[i]  = run;    // cursor
        run += c;
    }
    if (t == 1023) offsets[n] = part[1023];
}

// ============ fused phase A: compute + scatter payload to CSR slot ============
// angular blocks [0, nb_ang): 64B/pair = 32 fp16 [w0..15 | u0..15], full-line scatter
// radial  blocks [nb_ang, +nb_rad): 16B/edge = [f32 d | half2 pv01 | half2 pv23 | pad]
__global__ __launch_bounds__(256) void phaseA_kernel(
    const float* __restrict__ dist, const float* __restrict__ sw,
    const int* __restrict__ esrc, const int* __restrict__ edst,
    const float* __restrict__ ang_angles, const float* __restrict__ ang_dist,
    const float* __restrict__ ang_sw, const int* __restrict__ ang_edge_dst,
    const int* __restrict__ psrc, const int* __restrict__ pdst,
    const int* __restrict__ central,
    const float4* __restrict__ val_atom,
    int* __restrict__ rad_cursor, int* __restrict__ ang_cursor,
    uint4* __restrict__ ang_pay, uint4* __restrict__ rad_pay,
    int n_edges, int n_pairs, int nb_ang)
{
    int bid = blockIdx.x;
    int t = threadIdx.x;

    if (bid >= nb_ang) {
        // ---- radial ----
        int i = (bid - nb_ang) * 256 + t;
        if (i >= n_edges) return;
        float d  = dist[i];
        float ps = 0.25f * sw[i];
        float4 v = val_atom[edst[i]];
        uint4 rec;
        rec.x = __float_as_uint(d);
        rec.y = pack2(ps * v.x, ps * v.y);
        rec.z = pack2(ps * v.z, ps * v.w);
        rec.w = 0u;
        int slot = atomicAdd(&rad_cursor[esrc[i]], 1);
        rad_pay[slot] = rec;
        return;
    }

    // ---- angular ----
    int p = bid * 256 + t;
    if (p >= n_pairs) return;
    int e1 = psrc[p];
    int e2 = pdst[p];
    // issue all gathers up front
    float d1 = ang_dist[e1], d2 = ang_dist[e2];
    float s1 = ang_sw[e1],   s2 = ang_sw[e2];
    int a1 = ang_edge_dst[e1], a2 = ang_edge_dst[e2];
    float ang = ang_angles[p];
    int c = central[p];
    float4 v1 = val_atom[a1];
    float4 v2 = val_atom[a2];

    float d12 = 0.5f * (d1 + d2);
    float swp = 2.0f * s1 * s2;

    float sa, ca;
    __sincosf(ang, &sa, &ca);
    // cos(ang - shiftZ) = ca*cos(shiftZ) + sa*sin(shiftZ)
    const float czv[4] = { 0.92387953f,  0.38268343f, -0.38268343f, -0.92387953f };
    const float szv[4] = { 0.38268343f,  0.92387953f,  0.92387953f,  0.38268343f };
    float f1v[4], f2sv[4];
    #pragma unroll
    for (int z = 0; z < 4; ++z) {
        float y = 0.5f + 0.5f * (ca * czv[z] + sa * szv[z]);
        float y2 = y * y, y4 = y2 * y2, y8 = y4 * y4, y16 = y8 * y8;
        f1v[z] = y16 * y16;  // y^32
    }
    #pragma unroll
    for (int a = 0; a < 4; ++a) {
        float x = d12 - (0.8f + 0.675f * (float)a);
        f2sv[a] = swp * __expf(-8.0f * x * x);
    }
    float vp[4] = {v1.x + v2.x, v1.y + v2.y, v1.z + v2.z, v1.w + v2.w};
    float vm[4] = {v1.x * v2.x, v1.y * v2.y, v1.z * v2.z, v1.w * v2.w};

    float hv[32];
    #pragma unroll
    for (int a = 0; a < 4; ++a)
        #pragma unroll
        for (int z = 0; z < 4; ++z)
            hv[a * 4 + z] = f2sv[a] * f1v[z];        // w[az]
    #pragma unroll
    for (int i = 0; i < 4; ++i)
        #pragma unroll
        for (int j = 0; j < 4; ++j)
            hv[16 + i * 4 + j] = vp[i] * vm[j];      // u[ij]

    unsigned q[16];
    #pragma unroll
    for (int m = 0; m < 16; ++m) q[m] = pack2(hv[2 * m], hv[2 * m + 1]);

    int slot = atomicAdd(&ang_cursor[c], 1);
    uint4* dst = ang_pay + (size_t)slot * 4;
    dst[0] = make_uint4(q[0],  q[1],  q[2],  q[3]);
    dst[1] = make_uint4(q[4],  q[5],  q[6],  q[7]);
    dst[2] = make_uint4(q[8],  q[9],  q[10], q[11]);
    dst[3] = make_uint4(q[12], q[13], q[14], q[15]);
}

// ============ fused phase B: contiguous CSR reads ============
// blocks [0, n_atoms): angular (256 cols); [n_atoms, 2n): radial (64 cols) + onehot
__global__ __launch_bounds__(256) void phaseB_kernel(
    const uint4* __restrict__ ang_pay, const int* __restrict__ ang_offsets,
    const uint4* __restrict__ rad_pay, const int* __restrict__ rad_offsets,
    const int* __restrict__ species,
    float* __restrict__ out, int n_atoms)
{
    __shared__ float4 sbuf4_[512];            // 8 KB: stage [0,4KB) + part [4KB,8KB)
    float* sbuf = (float*)sbuf4_;
    uint4* stage = (uint4*)sbuf4_;
    float* part  = sbuf + 1024;

    int bid = blockIdx.x;
    int t = threadIdx.x;
    int w = t >> 6;                            // wave id 0..3

    if (bid < n_atoms) {
        // ---- angular ----
        int atom = bid;
        int beg = ang_offsets[atom];
        int end = ang_offsets[atom + 1];
        int lane = t & 63;
        int az = lane >> 2, i = lane & 3;      // col base = az*16 + i*4
        int cb = az * 16 + i * 4;
        float4 acc = make_float4(0.f, 0.f, 0.f, 0.f);
        const __half* hb = (const __half*)sbuf;
        for (int base = beg; base < end; base += 64) {
            int cnt = min(64, end - base);
            if (t < cnt * 4) stage[t] = ang_pay[(size_t)base * 4 + t];
            __syncthreads();
            for (int e = w; e < cnt; e += 4) {
                float wv = __half2float(hb[e * 32 + az]);          // broadcast u16
                const unsigned* ub = (const unsigned*)((const char*)sbuf + e * 64 + 32 + i * 8);
                float2 f01 = unpack2(ub[0]);
                float2 f23 = unpack2(ub[1]);
                acc.x += wv * f01.x;
                acc.y += wv * f01.y;
                acc.z += wv * f23.x;
                acc.w += wv * f23.y;
            }
            __syncthreads();
        }
        *(float4*)&part[w * 256 + cb] = acc;
        __syncthreads();
        float s = part[t] + part[256 + t] + part[512 + t] + part[768 + t];
        out[(size_t)atom * NCOLS + ANG_OFF + t] = s;
        return;
    }

    // ---- radial + onehot ----
    int atom = bid - n_atoms;
    int beg = rad_offsets[atom];
    int end = rad_offsets[atom + 1];
    int col = t & 63;
    int r = col >> 2, k = col & 3;
    float shift = 0.8f + 0.275f * (float)r;
    float acc = 0.0f;
    for (int base = beg; base < end; base += 64) {
        int cnt = min(64, end - base);
        if (t < cnt) stage[t] = rad_pay[(size_t)base + t];
        __syncthreads();
        for (int e = w; e < cnt; e += 4) {
            uint4 rec = stage[e];                                  // broadcast b128
            float d = __uint_as_float(rec.x);
            float2 f01 = unpack2(rec.y);
            float2 f23 = unpack2(rec.z);
            float pv = (k == 0) ? f01.x : (k == 1) ? f01.y : (k == 2) ? f23.x : f23.y;
            float x = d - shift;
            acc += __expf(-16.0f * x * x) * pv;
        }
        __syncthreads();
    }
    part[w * 64 + col] = acc;
    __syncthreads();
    if (t < 64) {
        float s = part[t] + part[64 + t] + part[128 + t] + part[192 + t];
        out[(size_t)atom * NCOLS + RAD_OFF + t] = s;
    }
    int sp = species[atom];
    if (t < 87) out[(size_t)atom * NCOLS + t] = (t == sp) ? 1.0f : 0.0f;
}

extern "C" void kernel_launch(void* const* d_in, const int* in_sizes, int n_in,
                              void* d_out, int out_size, void* d_ws, size_t ws_size,
                              hipStream_t stream) {
    const int*   species      = (const int*)  d_in[0];
    const float* distances    = (const float*)d_in[1];
    const float* switch_      = (const float*)d_in[2];
    const int*   edge_src     = (const int*)  d_in[3];
    const int*   edge_dst     = (const int*)  d_in[4];
    const float* ang_angles   = (const float*)d_in[5];
    const float* ang_dist     = (const float*)d_in[6];
    const float* ang_switch   = (const float*)d_in[7];
    const int*   ang_edge_dst = (const int*)  d_in[8];
    const int*   angle_src    = (const int*)  d_in[9];
    const int*   angle_dst    = (const int*)  d_in[10];
    const int*   central_atom = (const int*)  d_in[11];
    const float4* valence     = (const float4*)d_in[12];

    float* out = (float*)d_out;

    const int n_atoms = in_sizes[0];
    const int n_edges = in_sizes[1];
    const int n_pairs = in_sizes[5];

    // ---- workspace layout (16B-aligned), total ~= 46.5 MB ----
    char* ws = (char*)d_ws;
    size_t off = 0;
    auto alloc = [&](size_t bytes) -> void* {
        void* p = ws + off;
        off = (off + bytes + 15) & ~(size_t)15;
        return p;
    };
    uint4*  ang_pay     = (uint4*) alloc((size_t)n_pairs * 64);                 // 35.84 MB
    uint4*  rad_pay     = (uint4*) alloc((size_t)n_edges * 16);                 // 10.24 MB
    float4* val_atom    = (float4*)alloc((size_t)n_atoms * sizeof(float4));     //  0.32 MB
    int*    counts      = (int*)   alloc((size_t)2 * n_atoms * sizeof(int));    //  0.16 MB
    int*    rad_offsets = (int*)   alloc((size_t)(n_atoms + 1) * sizeof(int));
    int*    ang_offsets = (int*)   alloc((size_t)(n_atoms + 1) * sizeof(int));
    int* rad_counts = counts;            // doubles as cursor after scan
    int* ang_counts = counts + n_atoms;  // doubles as cursor after scan

    init_kernel<<<(2 * n_atoms + 255) / 256, 256, 0, stream>>>(
        species, valence, val_atom, counts, n_atoms);

    int n_work = n_edges + n_pairs;
    hist_kernel<<<(n_work + 255) / 256, 256, 0, stream>>>(
        edge_src, central_atom, rad_counts, ang_counts, n_edges, n_pairs);

    scan_kernel<<<2, 1024, 0, stream>>>(rad_counts, ang_counts, rad_offsets, ang_offsets, n_atoms);

    int nb_ang = (n_pairs + 255) / 256;
    int nb_rad = (n_edges + 255) / 256;
    phaseA_kernel<<<nb_ang + nb_rad, 256, 0, stream>>>(
        distances, switch_, edge_src, edge_dst,
        ang_angles, ang_dist, ang_switch, ang_edge_dst,
        angle_src, angle_dst, central_atom,
        val_atom, rad_counts, ang_counts,
        ang_pay, rad_pay, n_edges, n_pairs, nb_ang);

    phaseB_kernel<<<2 * n_atoms, 256, 0, stream>>>(
        ang_pay, ang_offsets, rad_pay, rad_offsets, species, out, n_atoms);
}